// Round 8
// baseline (294.617 us; speedup 1.0000x reference)
//
#include <hip/hip_runtime.h>

// ---------------------------------------------------------------------------
// GCN: out = agg(relu(agg(relu(agg(x)W0+b0))W1+b1) @ W2) + b2
// R8 = R7 + 2x-unrolled gather loops (8 loads in flight/lane; merges the two
//      latency exposures that ~45% of Poisson(16)-degree nodes incur) and
//      lane-guarded agg40 (only valid 80B of each t3 row loaded).
// ---------------------------------------------------------------------------

typedef short bf16x8 __attribute__((ext_vector_type(8)));
typedef float f32x4  __attribute__((ext_vector_type(4)));

#define EPB 8192   // edges per routing block

__device__ __forceinline__ float bflo(unsigned int v) {
  union { float f; unsigned int i; } w; w.i = v << 16; return w.f;
}
__device__ __forceinline__ float bfhi(unsigned int v) {
  union { float f; unsigned int i; } w; w.i = v & 0xffff0000u; return w.f;
}
__device__ __forceinline__ unsigned short f2bf(float f) {
  union { float f; unsigned int i; } w; w.f = f;
  unsigned int b = w.i;
  unsigned int r = (b + 0x7fffu + ((b >> 16) & 1u)) >> 16;   // RNE
  return (unsigned short)r;
}

__device__ __forceinline__ int edge_at(const void* ei, int is64, long long pos) {
  if (is64) return (int)((const long long*)ei)[pos];
  return ((const int*)ei)[pos];
}

__device__ __forceinline__ void agg_accum(float* a, uint4 v) {
  a[0] += bflo(v.x); a[1] += bfhi(v.x);
  a[2] += bflo(v.y); a[3] += bfhi(v.y);
  a[4] += bflo(v.z); a[5] += bfhi(v.z);
  a[6] += bflo(v.w); a[7] += bfhi(v.w);
}

// --------------------------- mega prep --------------------------------------
__global__ __launch_bounds__(256) void k_prep(const void* __restrict__ ei, int E,
                                              int* __restrict__ bhist,
                                              int NBKT, int NBLKE,
                                              const float* __restrict__ x,
                                              unsigned short* __restrict__ xb,
                                              long long n4, int ncvt,
                                              const float* __restrict__ W0,
                                              const float* __restrict__ W1,
                                              const float* __restrict__ W2,
                                              unsigned short* __restrict__ Wt0,
                                              unsigned short* __restrict__ Wt1,
                                              unsigned short* __restrict__ Wt2,
                                              unsigned short* __restrict__ bufH,
                                              unsigned short* __restrict__ t3,
                                              int FOUT, int N) {
  int blk = blockIdx.x, tid = threadIdx.x;
  if (blk < NBLKE) {
    __shared__ int h[512];
    __shared__ int s_is64;
    if (tid < 64) {
      int v = ((const int*)ei)[2 * tid + 1];
      unsigned long long m = __ballot(v != 0);
      if (tid == 0) s_is64 = (m == 0ull) ? 1 : 0;
    }
    for (int i = tid; i < NBKT; i += 256) h[i] = 0;
    __syncthreads();
    int is64 = s_is64;
    int base = blk * EPB;
    int cnt = min(EPB, E - base);
    for (int i = tid; i < cnt; i += 256) {
      int d = edge_at(ei, is64, (long long)E + base + i);
      atomicAdd(&h[d >> 8], 1);
    }
    __syncthreads();
    for (int i = tid; i < NBKT; i += 256) bhist[i * NBLKE + blk] = h[i];
  } else if (blk < NBLKE + ncvt) {
    long long i = (long long)(blk - NBLKE) * 256 + tid;
    if (i < n4) {
      float4 v = *reinterpret_cast<const float4*>(x + i * 4);
      ushort4 o;
      o.x = f2bf(v.x); o.y = f2bf(v.y); o.z = f2bf(v.z); o.w = f2bf(v.w);
      *reinterpret_cast<ushort4*>(xb + i * 4) = o;
    }
  } else {
    int idx = (blk - NBLKE - ncvt) * 256 + tid;
    if (idx < 16384) {
      int c = idx >> 7, k = idx & 127;
      Wt0[c * 128 + k] = f2bf(W0[k * 128 + c]);
    } else if (idx < 32768) {
      int t = idx - 16384;
      int c = t >> 7, k = t & 127;
      Wt1[c * 128 + k] = f2bf(W1[k * 128 + c]);
    } else if (idx < 40960) {                    // Wt2: 64 cols x 128
      int t = idx - 32768;
      int c = t >> 7, k = t & 127;
      Wt2[c * 128 + k] = (c < FOUT) ? f2bf(W2[k * FOUT + c]) : (unsigned short)0;
    } else if (idx < 41280) {                    // zero rows at index N
      int t = idx - 40960;
      if (t < 128)       xb[(size_t)N * 128 + t] = 0;
      else if (t < 256)  bufH[(size_t)N * 128 + (t - 128)] = 0;
      else               t3[(size_t)N * 64 + (t - 256)] = 0;
    }
  }
}

// --------------------------- scans ------------------------------------------
__global__ void k_scan_a(const int* __restrict__ vals, int* __restrict__ lscan,
                         int* __restrict__ partials, int n) {
  __shared__ int sm[256];
  int tid = threadIdx.x;
  int i = blockIdx.x * 256 + tid;
  int v = (i < n) ? vals[i] : 0;
  sm[tid] = v;
  __syncthreads();
  for (int off = 1; off < 256; off <<= 1) {
    int t = (tid >= off) ? sm[tid - off] : 0;
    __syncthreads();
    sm[tid] += t;
    __syncthreads();
  }
  if (i < n) lscan[i] = sm[tid];
  if (tid == 255) partials[blockIdx.x] = sm[255];
}

__global__ void k_scan_b(int* __restrict__ partials, int nb) {   // nb <= 1024
  __shared__ int sm[1024];
  int tid = threadIdx.x;
  int v = (tid < nb) ? partials[tid] : 0;
  sm[tid] = v;
  __syncthreads();
  for (int off = 1; off < 1024; off <<= 1) {
    int t = (tid >= off) ? sm[tid - off] : 0;
    __syncthreads();
    sm[tid] += t;
    __syncthreads();
  }
  if (tid < nb) partials[tid] = sm[tid] - v;   // exclusive
}

__global__ void k_scan_c(const int* __restrict__ lscan, const int* __restrict__ vals,
                         const int* __restrict__ partials, int* __restrict__ scanned,
                         int* __restrict__ bucketPtr, int n, int NBLKE, int NBKT, int E) {
  int i = blockIdx.x * 256 + threadIdx.x;
  if (i >= n) return;
  int v = lscan[i] - vals[i] + partials[blockIdx.x];
  scanned[i] = v;
  int q = i / NBLKE;
  if (i - q * NBLKE == 0) bucketPtr[q] = v;
  if (i == 0) bucketPtr[NBKT] = E;
}

// --------------------------- scatter + pass2 --------------------------------
__global__ __launch_bounds__(256) void b_scatter(const void* __restrict__ ei, int E,
                                                 const int* __restrict__ scanned,
                                                 unsigned* __restrict__ ebuf,
                                                 int NBKT, int NBLKE) {
  __shared__ int base[512];
  __shared__ int s_is64;
  int blk = blockIdx.x, tid = threadIdx.x;
  if (tid < 64) {
    int v = ((const int*)ei)[2 * tid + 1];
    unsigned long long m = __ballot(v != 0);
    if (tid == 0) s_is64 = (m == 0ull) ? 1 : 0;
  }
  for (int i = tid; i < NBKT; i += 256) base[i] = scanned[i * NBLKE + blk];
  __syncthreads();
  int is64 = s_is64;
  int b0 = blk * EPB;
  int cnt = min(EPB, E - b0);
  for (int i = tid; i < cnt; i += 256) {
    int d = edge_at(ei, is64, (long long)E + b0 + i);
    int s = edge_at(ei, is64, b0 + i);
    int pos = atomicAdd(&base[d >> 8], 1);
    ebuf[pos] = (unsigned)s | ((unsigned)(d & 255) << 24);
  }
}

__global__ __launch_bounds__(256) void b_pass2(const unsigned* __restrict__ ebuf,
                                               const int* __restrict__ bucketPtr,
                                               int* __restrict__ rowptr,
                                               int* __restrict__ colsrc,
                                               int N, int NBKT, int E) {
  __shared__ int hist[256], excl[256], cur[256], sm[256];
  int b = blockIdx.x, tid = threadIdx.x;
  hist[tid] = 0;
  __syncthreads();
  int beg = bucketPtr[b], end = bucketPtr[b + 1];
  for (int i = beg + tid; i < end; i += 256)
    atomicAdd(&hist[ebuf[i] >> 24], 1);
  __syncthreads();
  int v = hist[tid];
  sm[tid] = v;
  __syncthreads();
  for (int off = 1; off < 256; off <<= 1) {
    int t = (tid >= off) ? sm[tid - off] : 0;
    __syncthreads();
    sm[tid] += t;
    __syncthreads();
  }
  excl[tid] = sm[tid] - v;
  cur[tid] = 0;
  __syncthreads();
  int nb0 = b << 8;
  if (nb0 + tid < N) rowptr[nb0 + tid] = beg + excl[tid];
  if (b == 0 && tid == 0) rowptr[N] = E;
  for (int i = beg + tid; i < end; i += 256) {
    unsigned e2 = ebuf[i];
    int dl = (int)(e2 >> 24);
    int r = atomicAdd(&cur[dl], 1);
    colsrc[beg + excl[dl] + r] = (int)(e2 & 0xFFFFFFu);
  }
}

// --------------------------- aggregation ------------------------------------
// 128-wide bf16 agg: 1 wave/node, 2x-unrolled uniform loop: 32 edges/iter,
// 8 predicated 16B gathers in flight per lane (all statically indexed).
__global__ void k_agg128b(const char* __restrict__ Hb,
                          const int* __restrict__ rowptr, const int* __restrict__ colsrc,
                          unsigned int* __restrict__ out, int N) {
  int node = blockIdx.x * 4 + (threadIdx.x >> 6);
  if (node >= N) return;
  int l = threadIdx.x & 63, sub = l >> 4, fl = l & 15;
  int beg = rowptr[node], end = rowptr[node + 1];
  int nb = (end - beg + 31) >> 5;
  int em = end - 1;
  const unsigned zoff = (unsigned)N << 8;
  unsigned flo = (unsigned)fl * 16u;
  float a[8] = {0.f, 0.f, 0.f, 0.f, 0.f, 0.f, 0.f, 0.f};
  for (int t = 0; t < nb; ++t) {
    int e = beg + t * 32 + sub * 4;
    unsigned off[8];
    #pragma unroll
    for (int j = 0; j < 8; ++j) {
      int i = e + (j >> 2) * 16 + (j & 3);
      int s = colsrc[i < end ? i : em];
      off[j] = (i < end ? ((unsigned)s << 8) : zoff) + flo;
    }
    uint4 v[8];
    #pragma unroll
    for (int j = 0; j < 8; ++j)
      v[j] = *reinterpret_cast<const uint4*>(Hb + off[j]);
    #pragma unroll
    for (int j = 0; j < 8; ++j)
      agg_accum(a, v[j]);
  }
  #pragma unroll
  for (int k = 0; k < 8; ++k) {
    a[k] += __shfl_xor(a[k], 16);
    a[k] += __shfl_xor(a[k], 32);
  }
  if (sub == 0) {
    uint4 o;
    o.x = ((unsigned)f2bf(a[1]) << 16) | f2bf(a[0]);
    o.y = ((unsigned)f2bf(a[3]) << 16) | f2bf(a[2]);
    o.z = ((unsigned)f2bf(a[5]) << 16) | f2bf(a[4]);
    o.w = ((unsigned)f2bf(a[7]) << 16) | f2bf(a[6]);
    *reinterpret_cast<uint4*>(out + (size_t)node * 64 + fl * 4) = o;
  }
}

// 40-wide final agg from padded [N+1][64] bf16; out f32 [N][40] + b2.
// Only lanes fl<10 load (80B valid per row); 2x-unrolled, 8 loads in flight.
__global__ void k_agg40(const char* __restrict__ Tb,
                        const int* __restrict__ rowptr, const int* __restrict__ colsrc,
                        const float* __restrict__ b2, float* __restrict__ out, int N) {
  int node = blockIdx.x * 4 + (threadIdx.x >> 6);
  if (node >= N) return;
  int l = threadIdx.x & 63, sub = l >> 4, fl = l & 15;
  int beg = rowptr[node], end = rowptr[node + 1];
  int nb = (end - beg + 31) >> 5;
  int em = end - 1;
  const unsigned zoff = (unsigned)N << 7;
  unsigned flo = (unsigned)fl * 8u;
  float a[4] = {0.f, 0.f, 0.f, 0.f};
  if (fl < 10) {
    for (int t = 0; t < nb; ++t) {
      int e = beg + t * 32 + sub * 4;
      unsigned off[8];
      #pragma unroll
      for (int j = 0; j < 8; ++j) {
        int i = e + (j >> 2) * 16 + (j & 3);
        int s = colsrc[i < end ? i : em];
        off[j] = (i < end ? ((unsigned)s << 7) : zoff) + flo;
      }
      uint2 v[8];
      #pragma unroll
      for (int j = 0; j < 8; ++j)
        v[j] = *reinterpret_cast<const uint2*>(Tb + off[j]);
      #pragma unroll
      for (int j = 0; j < 8; ++j) {
        a[0] += bflo(v[j].x); a[1] += bfhi(v[j].x);
        a[2] += bflo(v[j].y); a[3] += bfhi(v[j].y);
      }
    }
  }
  #pragma unroll
  for (int k = 0; k < 4; ++k) {
    a[k] += __shfl_xor(a[k], 16);
    a[k] += __shfl_xor(a[k], 32);
  }
  if (sub == 0 && fl < 10) {
    float4 o;
    o.x = a[0] + b2[fl * 4 + 0];
    o.y = a[1] + b2[fl * 4 + 1];
    o.z = a[2] + b2[fl * 4 + 2];
    o.w = a[3] + b2[fl * 4 + 3];
    *reinterpret_cast<float4*>(out + (size_t)node * 40 + fl * 4) = o;
  }
}

// --------------------------- GEMM (MFMA bf16) -------------------------------
// CHAIN=0: C[N][128] = relu(A@Wt + bias)
// CHAIN=1: C[N][64]  = (relu(A@Wt + bias)) @ Wt2   (C2 staged in wave-LDS)
template <int CHAIN>
__global__ __launch_bounds__(256) void k_gemm(const unsigned short* __restrict__ A,
                                              const unsigned short* __restrict__ Wt,
                                              const float* __restrict__ bias,
                                              const unsigned short* __restrict__ Wt2,
                                              unsigned short* __restrict__ C, int N) {
  __shared__ unsigned short sh16[CHAIN ? 4 * 2048 : 64];   // 16 KB when chaining
  int tid = threadIdx.x;
  int w = tid >> 6, l = tid & 63;
  int sub = l >> 4, fl = l & 15;
  int r0 = blockIdx.x * 64 + w * 16;
  int arow = r0 + fl;
  if (arow >= N) arow = N - 1;
  int kk = sub * 8;
  bf16x8 af[4];
  #pragma unroll
  for (int ks = 0; ks < 4; ++ks)
    af[ks] = *reinterpret_cast<const bf16x8*>(A + (size_t)arow * 128 + ks * 32 + kk);

  int ccol = fl;
  int crow0 = r0 + sub * 4;

  if (CHAIN == 0) {
    #pragma unroll
    for (int cf = 0; cf < 8; ++cf) {
      f32x4 acc = {0.f, 0.f, 0.f, 0.f};
      const unsigned short* wp = Wt + (size_t)(cf * 16 + ccol) * 128 + kk;
      #pragma unroll
      for (int ks = 0; ks < 4; ++ks) {
        bf16x8 b = *reinterpret_cast<const bf16x8*>(wp + ks * 32);
        acc = __builtin_amdgcn_mfma_f32_16x16x32_bf16(af[ks], b, acc, 0, 0, 0);
      }
      float bv = bias[cf * 16 + ccol];
      #pragma unroll
      for (int r = 0; r < 4; ++r) {
        int gr = crow0 + r;
        if (gr < N)
          C[(size_t)gr * 128 + cf * 16 + ccol] = f2bf(fmaxf(acc[r] + bv, 0.f));
      }
    }
  } else {
    unsigned short* my = &sh16[w * 2048];
    #pragma unroll
    for (int cf = 0; cf < 8; ++cf) {
      f32x4 acc = {0.f, 0.f, 0.f, 0.f};
      const unsigned short* wp = Wt + (size_t)(cf * 16 + ccol) * 128 + kk;
      #pragma unroll
      for (int ks = 0; ks < 4; ++ks) {
        bf16x8 b = *reinterpret_cast<const bf16x8*>(wp + ks * 32);
        acc = __builtin_amdgcn_mfma_f32_16x16x32_bf16(af[ks], b, acc, 0, 0, 0);
      }
      float bv = bias[cf * 16 + ccol];
      int col = cf * 16 + ccol;
      int chunk = col >> 3;
      #pragma unroll
      for (int r = 0; r < 4; ++r) {
        int row = sub * 4 + r;
        my[row * 128 + ((chunk ^ row) << 3) + (col & 7)] = f2bf(fmaxf(acc[r] + bv, 0.f));
      }
    }
    // second GEMM: A3 = C2 tile (rows = fl), k-chunks swizzle-read from LDS
    bf16x8 af3[4];
    #pragma unroll
    for (int ks = 0; ks < 4; ++ks) {
      int c = ks * 4 + sub;
      af3[ks] = *reinterpret_cast<const bf16x8*>(&my[fl * 128 + ((c ^ fl) << 3)]);
    }
    #pragma unroll
    for (int cf = 0; cf < 4; ++cf) {                   // 64 cols
      f32x4 acc = {0.f, 0.f, 0.f, 0.f};
      const unsigned short* wp = Wt2 + (size_t)(cf * 16 + ccol) * 128 + kk;
      #pragma unroll
      for (int ks = 0; ks < 4; ++ks) {
        bf16x8 b = *reinterpret_cast<const bf16x8*>(wp + ks * 32);
        acc = __builtin_amdgcn_mfma_f32_16x16x32_bf16(af3[ks], b, acc, 0, 0, 0);
      }
      #pragma unroll
      for (int r = 0; r < 4; ++r) {
        int gr = crow0 + r;
        if (gr < N)
          C[(size_t)gr * 64 + cf * 16 + ccol] = f2bf(acc[r]);
      }
    }
  }
}

extern "C" void kernel_launch(void* const* d_in, const int* in_sizes, int n_in,
                              void* d_out, int out_size, void* d_ws, size_t ws_size,
                              hipStream_t stream) {
  const float* x  = (const float*)d_in[0];
  const void*  ei = d_in[1];
  const float* W0 = (const float*)d_in[2];
  const float* b0 = (const float*)d_in[3];
  const float* W1 = (const float*)d_in[4];
  const float* b1 = (const float*)d_in[5];
  const float* W2 = (const float*)d_in[6];
  const float* b2 = (const float*)d_in[7];
  float* out = (float*)d_out;

  const int N = in_sizes[0] / 128;     // 100000
  const int E = in_sizes[1] / 2;       // 1600000
  const int FOUT = in_sizes[6] / 128;  // 40

  const int NBLKE = (E + EPB - 1) / EPB;        // 196
  const int NBKT  = (N + 255) / 256;            // 391
  const int T     = NBKT * NBLKE;               // 76,636
  const int GS    = (T + 255) / 256;            // 300 (<=1024)

  char* wp = (char*)d_ws;
  auto alloc = [&](size_t bytes) -> void* {
    void* p = (void*)wp;
    wp += (bytes + 255) & ~(size_t)255;
    return p;
  };
  unsigned short* xb   = (unsigned short*)alloc((size_t)(N + 1) * 128 * 2);
  unsigned short* bufA = (unsigned short*)alloc((size_t)N * 128 * 2);
  unsigned short* bufH = (unsigned short*)alloc((size_t)(N + 1) * 128 * 2);
  unsigned short* t3   = (unsigned short*)alloc((size_t)(N + 1) * 64 * 2);
  unsigned short* Wt0  = (unsigned short*)alloc(128 * 128 * 2);
  unsigned short* Wt1  = (unsigned short*)alloc(128 * 128 * 2);
  unsigned short* Wt2  = (unsigned short*)alloc(64 * 128 * 2);
  unsigned* ebuf = (unsigned*)alloc((size_t)E * 4);
  int* colsrc   = (int*)alloc((size_t)E * 4);
  int* rowptr   = (int*)alloc((size_t)(N + 1) * 4);
  int* bhist    = (int*)alloc((size_t)T * 4);
  int* lscan    = (int*)alloc((size_t)T * 4);
  int* scanned  = (int*)alloc((size_t)T * 4);
  int* partials = (int*)alloc(4096);
  int* bucketPtr= (int*)alloc((size_t)(NBKT + 1) * 4);

  long long n4 = (long long)N * 32;
  int ncvt = (int)((n4 + 255) / 256);           // 12500
  int nwt  = (40960 + 320 + 255) / 256;         // 162

  k_prep<<<NBLKE + ncvt + nwt, 256, 0, stream>>>(ei, E, bhist, NBKT, NBLKE,
                                                 x, xb, n4, ncvt,
                                                 W0, W1, W2, Wt0, Wt1, Wt2,
                                                 bufH, t3, FOUT, N);
  k_scan_a<<<GS, 256, 0, stream>>>(bhist, lscan, partials, T);
  k_scan_b<<<1, 1024, 0, stream>>>(partials, GS);
  k_scan_c<<<GS, 256, 0, stream>>>(lscan, bhist, partials, scanned, bucketPtr,
                                   T, NBLKE, NBKT, E);
  b_scatter<<<NBLKE, 256, 0, stream>>>(ei, E, scanned, ebuf, NBKT, NBLKE);
  b_pass2<<<NBKT, 256, 0, stream>>>(ebuf, bucketPtr, rowptr, colsrc, N, NBKT, E);

  int gagg = (N + 3) / 4;
  int ggemm = (N + 63) / 64;
  // layer 1: h1 = relu(agg(x)@W0+b0)
  k_agg128b<<<gagg, 256, 0, stream>>>((const char*)xb, rowptr, colsrc,
                                      (unsigned int*)bufA, N);
  k_gemm<0><<<ggemm, 256, 0, stream>>>(bufA, Wt0, b0, nullptr, bufH, N);
  // layers 2+3a: t3 = relu(agg(h1)@W1+b1) @ W2   (h2 never materialized)
  k_agg128b<<<gagg, 256, 0, stream>>>((const char*)bufH, rowptr, colsrc,
                                      (unsigned int*)bufA, N);
  k_gemm<1><<<ggemm, 256, 0, stream>>>(bufA, Wt1, b1, Wt2, t3, N);
  // layer 3b: out = agg(t3) + b2
  k_agg40<<<gagg, 256, 0, stream>>>((const char*)t3, rowptr, colsrc, b2, out, N);
}

// Round 9
// 286.305 us; speedup vs baseline: 1.0290x; 1.0290x over previous
//
#include <hip/hip_runtime.h>

// ---------------------------------------------------------------------------
// GCN: out = agg(relu(agg(relu(agg(x)W0+b0))W1+b1) @ W2) + b2
// R9 = R7 agg (best config: 4 loads in flight, 28 VGPR, 66% occ)
//      + agg40 lane guard (fl<10)
//      + EPB 2048 (hist/scatter: 196 -> 782 blocks, fixes CSR-build TLP hole)
//      + scan_b handles 2048 partials (2 elems/thread).
// ---------------------------------------------------------------------------

typedef short bf16x8 __attribute__((ext_vector_type(8)));
typedef float f32x4  __attribute__((ext_vector_type(4)));

#define EPB 2048   // edges per routing block

__device__ __forceinline__ float bflo(unsigned int v) {
  union { float f; unsigned int i; } w; w.i = v << 16; return w.f;
}
__device__ __forceinline__ float bfhi(unsigned int v) {
  union { float f; unsigned int i; } w; w.i = v & 0xffff0000u; return w.f;
}
__device__ __forceinline__ unsigned short f2bf(float f) {
  union { float f; unsigned int i; } w; w.f = f;
  unsigned int b = w.i;
  unsigned int r = (b + 0x7fffu + ((b >> 16) & 1u)) >> 16;   // RNE
  return (unsigned short)r;
}

__device__ __forceinline__ int edge_at(const void* ei, int is64, long long pos) {
  if (is64) return (int)((const long long*)ei)[pos];
  return ((const int*)ei)[pos];
}

__device__ __forceinline__ void agg_accum(float* a, uint4 v) {
  a[0] += bflo(v.x); a[1] += bfhi(v.x);
  a[2] += bflo(v.y); a[3] += bfhi(v.y);
  a[4] += bflo(v.z); a[5] += bfhi(v.z);
  a[6] += bflo(v.w); a[7] += bfhi(v.w);
}

// --------------------------- mega prep --------------------------------------
__global__ __launch_bounds__(256) void k_prep(const void* __restrict__ ei, int E,
                                              int* __restrict__ bhist,
                                              int NBKT, int NBLKE,
                                              const float* __restrict__ x,
                                              unsigned short* __restrict__ xb,
                                              long long n4, int ncvt,
                                              const float* __restrict__ W0,
                                              const float* __restrict__ W1,
                                              const float* __restrict__ W2,
                                              unsigned short* __restrict__ Wt0,
                                              unsigned short* __restrict__ Wt1,
                                              unsigned short* __restrict__ Wt2,
                                              unsigned short* __restrict__ bufH,
                                              unsigned short* __restrict__ t3,
                                              int FOUT, int N) {
  int blk = blockIdx.x, tid = threadIdx.x;
  if (blk < NBLKE) {
    __shared__ int h[512];
    __shared__ int s_is64;
    if (tid < 64) {
      int v = ((const int*)ei)[2 * tid + 1];
      unsigned long long m = __ballot(v != 0);
      if (tid == 0) s_is64 = (m == 0ull) ? 1 : 0;
    }
    for (int i = tid; i < NBKT; i += 256) h[i] = 0;
    __syncthreads();
    int is64 = s_is64;
    int base = blk * EPB;
    int cnt = min(EPB, E - base);
    for (int i = tid; i < cnt; i += 256) {
      int d = edge_at(ei, is64, (long long)E + base + i);
      atomicAdd(&h[d >> 8], 1);
    }
    __syncthreads();
    for (int i = tid; i < NBKT; i += 256) bhist[i * NBLKE + blk] = h[i];
  } else if (blk < NBLKE + ncvt) {
    long long i = (long long)(blk - NBLKE) * 256 + tid;
    if (i < n4) {
      float4 v = *reinterpret_cast<const float4*>(x + i * 4);
      ushort4 o;
      o.x = f2bf(v.x); o.y = f2bf(v.y); o.z = f2bf(v.z); o.w = f2bf(v.w);
      *reinterpret_cast<ushort4*>(xb + i * 4) = o;
    }
  } else {
    int idx = (blk - NBLKE - ncvt) * 256 + tid;
    if (idx < 16384) {
      int c = idx >> 7, k = idx & 127;
      Wt0[c * 128 + k] = f2bf(W0[k * 128 + c]);
    } else if (idx < 32768) {
      int t = idx - 16384;
      int c = t >> 7, k = t & 127;
      Wt1[c * 128 + k] = f2bf(W1[k * 128 + c]);
    } else if (idx < 40960) {                    // Wt2: 64 cols x 128
      int t = idx - 32768;
      int c = t >> 7, k = t & 127;
      Wt2[c * 128 + k] = (c < FOUT) ? f2bf(W2[k * FOUT + c]) : (unsigned short)0;
    } else if (idx < 41280) {                    // zero rows at index N
      int t = idx - 40960;
      if (t < 128)       xb[(size_t)N * 128 + t] = 0;
      else if (t < 256)  bufH[(size_t)N * 128 + (t - 128)] = 0;
      else               t3[(size_t)N * 64 + (t - 256)] = 0;
    }
  }
}

// --------------------------- scans ------------------------------------------
__global__ void k_scan_a(const int* __restrict__ vals, int* __restrict__ lscan,
                         int* __restrict__ partials, int n) {
  __shared__ int sm[256];
  int tid = threadIdx.x;
  int i = blockIdx.x * 256 + tid;
  int v = (i < n) ? vals[i] : 0;
  sm[tid] = v;
  __syncthreads();
  for (int off = 1; off < 256; off <<= 1) {
    int t = (tid >= off) ? sm[tid - off] : 0;
    __syncthreads();
    sm[tid] += t;
    __syncthreads();
  }
  if (i < n) lscan[i] = sm[tid];
  if (tid == 255) partials[blockIdx.x] = sm[255];
}

// exclusive scan of up to 2048 partials (2 elems/thread, 1024 threads)
__global__ void k_scan_b(int* __restrict__ partials, int nb) {
  __shared__ int sm[1024];
  int tid = threadIdx.x;
  int i0 = 2 * tid, i1 = 2 * tid + 1;
  int v0 = (i0 < nb) ? partials[i0] : 0;
  int v1 = (i1 < nb) ? partials[i1] : 0;
  int s = v0 + v1;
  sm[tid] = s;
  __syncthreads();
  for (int off = 1; off < 1024; off <<= 1) {
    int t = (tid >= off) ? sm[tid - off] : 0;
    __syncthreads();
    sm[tid] += t;
    __syncthreads();
  }
  int excl = sm[tid] - s;
  if (i0 < nb) partials[i0] = excl;
  if (i1 < nb) partials[i1] = excl + v0;
}

__global__ void k_scan_c(const int* __restrict__ lscan, const int* __restrict__ vals,
                         const int* __restrict__ partials, int* __restrict__ scanned,
                         int* __restrict__ bucketPtr, int n, int NBLKE, int NBKT, int E) {
  int i = blockIdx.x * 256 + threadIdx.x;
  if (i >= n) return;
  int v = lscan[i] - vals[i] + partials[blockIdx.x];
  scanned[i] = v;
  int q = i / NBLKE;
  if (i - q * NBLKE == 0) bucketPtr[q] = v;
  if (i == 0) bucketPtr[NBKT] = E;
}

// --------------------------- scatter + pass2 --------------------------------
__global__ __launch_bounds__(256) void b_scatter(const void* __restrict__ ei, int E,
                                                 const int* __restrict__ scanned,
                                                 unsigned* __restrict__ ebuf,
                                                 int NBKT, int NBLKE) {
  __shared__ int base[512];
  __shared__ int s_is64;
  int blk = blockIdx.x, tid = threadIdx.x;
  if (tid < 64) {
    int v = ((const int*)ei)[2 * tid + 1];
    unsigned long long m = __ballot(v != 0);
    if (tid == 0) s_is64 = (m == 0ull) ? 1 : 0;
  }
  for (int i = tid; i < NBKT; i += 256) base[i] = scanned[i * NBLKE + blk];
  __syncthreads();
  int is64 = s_is64;
  int b0 = blk * EPB;
  int cnt = min(EPB, E - b0);
  for (int i = tid; i < cnt; i += 256) {
    int d = edge_at(ei, is64, (long long)E + b0 + i);
    int s = edge_at(ei, is64, b0 + i);
    int pos = atomicAdd(&base[d >> 8], 1);
    ebuf[pos] = (unsigned)s | ((unsigned)(d & 255) << 24);
  }
}

__global__ __launch_bounds__(256) void b_pass2(const unsigned* __restrict__ ebuf,
                                               const int* __restrict__ bucketPtr,
                                               int* __restrict__ rowptr,
                                               int* __restrict__ colsrc,
                                               int N, int NBKT, int E) {
  __shared__ int hist[256], excl[256], cur[256], sm[256];
  int b = blockIdx.x, tid = threadIdx.x;
  hist[tid] = 0;
  __syncthreads();
  int beg = bucketPtr[b], end = bucketPtr[b + 1];
  for (int i = beg + tid; i < end; i += 256)
    atomicAdd(&hist[ebuf[i] >> 24], 1);
  __syncthreads();
  int v = hist[tid];
  sm[tid] = v;
  __syncthreads();
  for (int off = 1; off < 256; off <<= 1) {
    int t = (tid >= off) ? sm[tid - off] : 0;
    __syncthreads();
    sm[tid] += t;
    __syncthreads();
  }
  excl[tid] = sm[tid] - v;
  cur[tid] = 0;
  __syncthreads();
  int nb0 = b << 8;
  if (nb0 + tid < N) rowptr[nb0 + tid] = beg + excl[tid];
  if (b == 0 && tid == 0) rowptr[N] = E;
  for (int i = beg + tid; i < end; i += 256) {
    unsigned e2 = ebuf[i];
    int dl = (int)(e2 >> 24);
    int r = atomicAdd(&cur[dl], 1);
    colsrc[beg + excl[dl] + r] = (int)(e2 & 0xFFFFFFu);
  }
}

// --------------------------- aggregation ------------------------------------
// 128-wide bf16 agg: 1 wave/node, uniform trip count, zero-row predication,
// 4x 16B gathers in flight per lane (R7 sweet spot: 28 VGPR, ~66% occ).
__global__ void k_agg128b(const char* __restrict__ Hb,
                          const int* __restrict__ rowptr, const int* __restrict__ colsrc,
                          unsigned int* __restrict__ out, int N) {
  int node = blockIdx.x * 4 + (threadIdx.x >> 6);
  if (node >= N) return;
  int l = threadIdx.x & 63, sub = l >> 4, fl = l & 15;
  int beg = rowptr[node], end = rowptr[node + 1];
  int nb = (end - beg + 15) >> 4;
  const unsigned zoff = (unsigned)N << 8;
  unsigned flo = (unsigned)fl * 16u;
  float a[8] = {0.f, 0.f, 0.f, 0.f, 0.f, 0.f, 0.f, 0.f};
  for (int t = 0; t < nb; ++t) {
    int e = beg + t * 16 + sub * 4;
    int em = end - 1;
    int i0 = e, i1 = e + 1, i2 = e + 2, i3 = e + 3;
    int s0 = colsrc[i0 < end ? i0 : em];
    int s1 = colsrc[i1 < end ? i1 : em];
    int s2 = colsrc[i2 < end ? i2 : em];
    int s3 = colsrc[i3 < end ? i3 : em];
    unsigned o0 = (i0 < end ? ((unsigned)s0 << 8) : zoff) + flo;
    unsigned o1 = (i1 < end ? ((unsigned)s1 << 8) : zoff) + flo;
    unsigned o2 = (i2 < end ? ((unsigned)s2 << 8) : zoff) + flo;
    unsigned o3 = (i3 < end ? ((unsigned)s3 << 8) : zoff) + flo;
    uint4 v0 = *reinterpret_cast<const uint4*>(Hb + o0);
    uint4 v1 = *reinterpret_cast<const uint4*>(Hb + o1);
    uint4 v2 = *reinterpret_cast<const uint4*>(Hb + o2);
    uint4 v3 = *reinterpret_cast<const uint4*>(Hb + o3);
    agg_accum(a, v0); agg_accum(a, v1); agg_accum(a, v2); agg_accum(a, v3);
  }
  #pragma unroll
  for (int k = 0; k < 8; ++k) {
    a[k] += __shfl_xor(a[k], 16);
    a[k] += __shfl_xor(a[k], 32);
  }
  if (sub == 0) {
    uint4 o;
    o.x = ((unsigned)f2bf(a[1]) << 16) | f2bf(a[0]);
    o.y = ((unsigned)f2bf(a[3]) << 16) | f2bf(a[2]);
    o.z = ((unsigned)f2bf(a[5]) << 16) | f2bf(a[4]);
    o.w = ((unsigned)f2bf(a[7]) << 16) | f2bf(a[6]);
    *reinterpret_cast<uint4*>(out + (size_t)node * 64 + fl * 4) = o;
  }
}

// 40-wide final agg from padded [N+1][64] bf16; out f32 [N][40] + b2.
// Only lanes fl<10 load (80B valid per row); R7 loop shape.
__global__ void k_agg40(const char* __restrict__ Tb,
                        const int* __restrict__ rowptr, const int* __restrict__ colsrc,
                        const float* __restrict__ b2, float* __restrict__ out, int N) {
  int node = blockIdx.x * 4 + (threadIdx.x >> 6);
  if (node >= N) return;
  int l = threadIdx.x & 63, sub = l >> 4, fl = l & 15;
  int beg = rowptr[node], end = rowptr[node + 1];
  int nb = (end - beg + 15) >> 4;
  const unsigned zoff = (unsigned)N << 7;
  unsigned flo = (unsigned)fl * 8u;
  float a[4] = {0.f, 0.f, 0.f, 0.f};
  if (fl < 10) {
    for (int t = 0; t < nb; ++t) {
      int e = beg + t * 16 + sub * 4;
      int em = end - 1;
      int i0 = e, i1 = e + 1, i2 = e + 2, i3 = e + 3;
      int s0 = colsrc[i0 < end ? i0 : em];
      int s1 = colsrc[i1 < end ? i1 : em];
      int s2 = colsrc[i2 < end ? i2 : em];
      int s3 = colsrc[i3 < end ? i3 : em];
      unsigned o0 = (i0 < end ? ((unsigned)s0 << 7) : zoff) + flo;
      unsigned o1 = (i1 < end ? ((unsigned)s1 << 7) : zoff) + flo;
      unsigned o2 = (i2 < end ? ((unsigned)s2 << 7) : zoff) + flo;
      unsigned o3 = (i3 < end ? ((unsigned)s3 << 7) : zoff) + flo;
      uint2 v0 = *reinterpret_cast<const uint2*>(Tb + o0);
      uint2 v1 = *reinterpret_cast<const uint2*>(Tb + o1);
      uint2 v2 = *reinterpret_cast<const uint2*>(Tb + o2);
      uint2 v3 = *reinterpret_cast<const uint2*>(Tb + o3);
      a[0] += (bflo(v0.x) + bflo(v1.x)) + (bflo(v2.x) + bflo(v3.x));
      a[1] += (bfhi(v0.x) + bfhi(v1.x)) + (bfhi(v2.x) + bfhi(v3.x));
      a[2] += (bflo(v0.y) + bflo(v1.y)) + (bflo(v2.y) + bflo(v3.y));
      a[3] += (bfhi(v0.y) + bfhi(v1.y)) + (bfhi(v2.y) + bfhi(v3.y));
    }
  }
  #pragma unroll
  for (int k = 0; k < 4; ++k) {
    a[k] += __shfl_xor(a[k], 16);
    a[k] += __shfl_xor(a[k], 32);
  }
  if (sub == 0 && fl < 10) {
    float4 o;
    o.x = a[0] + b2[fl * 4 + 0];
    o.y = a[1] + b2[fl * 4 + 1];
    o.z = a[2] + b2[fl * 4 + 2];
    o.w = a[3] + b2[fl * 4 + 3];
    *reinterpret_cast<float4*>(out + (size_t)node * 40 + fl * 4) = o;
  }
}

// --------------------------- GEMM (MFMA bf16) -------------------------------
// CHAIN=0: C[N][128] = relu(A@Wt + bias)
// CHAIN=1: C[N][64]  = (relu(A@Wt + bias)) @ Wt2   (C2 staged in wave-LDS)
template <int CHAIN>
__global__ __launch_bounds__(256) void k_gemm(const unsigned short* __restrict__ A,
                                              const unsigned short* __restrict__ Wt,
                                              const float* __restrict__ bias,
                                              const unsigned short* __restrict__ Wt2,
                                              unsigned short* __restrict__ C, int N) {
  __shared__ unsigned short sh16[CHAIN ? 4 * 2048 : 64];   // 16 KB when chaining
  int tid = threadIdx.x;
  int w = tid >> 6, l = tid & 63;
  int sub = l >> 4, fl = l & 15;
  int r0 = blockIdx.x * 64 + w * 16;
  int arow = r0 + fl;
  if (arow >= N) arow = N - 1;
  int kk = sub * 8;
  bf16x8 af[4];
  #pragma unroll
  for (int ks = 0; ks < 4; ++ks)
    af[ks] = *reinterpret_cast<const bf16x8*>(A + (size_t)arow * 128 + ks * 32 + kk);

  int ccol = fl;
  int crow0 = r0 + sub * 4;

  if (CHAIN == 0) {
    #pragma unroll
    for (int cf = 0; cf < 8; ++cf) {
      f32x4 acc = {0.f, 0.f, 0.f, 0.f};
      const unsigned short* wp = Wt + (size_t)(cf * 16 + ccol) * 128 + kk;
      #pragma unroll
      for (int ks = 0; ks < 4; ++ks) {
        bf16x8 b = *reinterpret_cast<const bf16x8*>(wp + ks * 32);
        acc = __builtin_amdgcn_mfma_f32_16x16x32_bf16(af[ks], b, acc, 0, 0, 0);
      }
      float bv = bias[cf * 16 + ccol];
      #pragma unroll
      for (int r = 0; r < 4; ++r) {
        int gr = crow0 + r;
        if (gr < N)
          C[(size_t)gr * 128 + cf * 16 + ccol] = f2bf(fmaxf(acc[r] + bv, 0.f));
      }
    }
  } else {
    unsigned short* my = &sh16[w * 2048];
    #pragma unroll
    for (int cf = 0; cf < 8; ++cf) {
      f32x4 acc = {0.f, 0.f, 0.f, 0.f};
      const unsigned short* wp = Wt + (size_t)(cf * 16 + ccol) * 128 + kk;
      #pragma unroll
      for (int ks = 0; ks < 4; ++ks) {
        bf16x8 b = *reinterpret_cast<const bf16x8*>(wp + ks * 32);
        acc = __builtin_amdgcn_mfma_f32_16x16x32_bf16(af[ks], b, acc, 0, 0, 0);
      }
      float bv = bias[cf * 16 + ccol];
      int col = cf * 16 + ccol;
      int chunk = col >> 3;
      #pragma unroll
      for (int r = 0; r < 4; ++r) {
        int row = sub * 4 + r;
        my[row * 128 + ((chunk ^ row) << 3) + (col & 7)] = f2bf(fmaxf(acc[r] + bv, 0.f));
      }
    }
    // second GEMM: A3 = C2 tile (rows = fl), k-chunks swizzle-read from LDS
    bf16x8 af3[4];
    #pragma unroll
    for (int ks = 0; ks < 4; ++ks) {
      int c = ks * 4 + sub;
      af3[ks] = *reinterpret_cast<const bf16x8*>(&my[fl * 128 + ((c ^ fl) << 3)]);
    }
    #pragma unroll
    for (int cf = 0; cf < 4; ++cf) {                   // 64 cols
      f32x4 acc = {0.f, 0.f, 0.f, 0.f};
      const unsigned short* wp = Wt2 + (size_t)(cf * 16 + ccol) * 128 + kk;
      #pragma unroll
      for (int ks = 0; ks < 4; ++ks) {
        bf16x8 b = *reinterpret_cast<const bf16x8*>(wp + ks * 32);
        acc = __builtin_amdgcn_mfma_f32_16x16x32_bf16(af3[ks], b, acc, 0, 0, 0);
      }
      #pragma unroll
      for (int r = 0; r < 4; ++r) {
        int gr = crow0 + r;
        if (gr < N)
          C[(size_t)gr * 64 + cf * 16 + ccol] = f2bf(acc[r]);
      }
    }
  }
}

extern "C" void kernel_launch(void* const* d_in, const int* in_sizes, int n_in,
                              void* d_out, int out_size, void* d_ws, size_t ws_size,
                              hipStream_t stream) {
  const float* x  = (const float*)d_in[0];
  const void*  ei = d_in[1];
  const float* W0 = (const float*)d_in[2];
  const float* b0 = (const float*)d_in[3];
  const float* W1 = (const float*)d_in[4];
  const float* b1 = (const float*)d_in[5];
  const float* W2 = (const float*)d_in[6];
  const float* b2 = (const float*)d_in[7];
  float* out = (float*)d_out;

  const int N = in_sizes[0] / 128;     // 100000
  const int E = in_sizes[1] / 2;       // 1600000
  const int FOUT = in_sizes[6] / 128;  // 40

  const int NBLKE = (E + EPB - 1) / EPB;        // 782
  const int NBKT  = (N + 255) / 256;            // 391
  const int T     = NBKT * NBLKE;               // 305,762
  const int GS    = (T + 255) / 256;            // 1195 (<=2048 for scan_b)

  char* wp = (char*)d_ws;
  auto alloc = [&](size_t bytes) -> void* {
    void* p = (void*)wp;
    wp += (bytes + 255) & ~(size_t)255;
    return p;
  };
  unsigned short* xb   = (unsigned short*)alloc((size_t)(N + 1) * 128 * 2);
  unsigned short* bufA = (unsigned short*)alloc((size_t)N * 128 * 2);
  unsigned short* bufH = (unsigned short*)alloc((size_t)(N + 1) * 128 * 2);
  unsigned short* t3   = (unsigned short*)alloc((size_t)(N + 1) * 64 * 2);
  unsigned short* Wt0  = (unsigned short*)alloc(128 * 128 * 2);
  unsigned short* Wt1  = (unsigned short*)alloc(128 * 128 * 2);
  unsigned short* Wt2  = (unsigned short*)alloc(64 * 128 * 2);
  unsigned* ebuf = (unsigned*)alloc((size_t)E * 4);
  int* colsrc   = (int*)alloc((size_t)E * 4);
  int* rowptr   = (int*)alloc((size_t)(N + 1) * 4);
  int* bhist    = (int*)alloc((size_t)T * 4);
  int* lscan    = (int*)alloc((size_t)T * 4);
  int* scanned  = (int*)alloc((size_t)T * 4);
  int* partials = (int*)alloc(8192);
  int* bucketPtr= (int*)alloc((size_t)(NBKT + 1) * 4);

  long long n4 = (long long)N * 32;
  int ncvt = (int)((n4 + 255) / 256);           // 12500
  int nwt  = (40960 + 320 + 255) / 256;         // 162

  k_prep<<<NBLKE + ncvt + nwt, 256, 0, stream>>>(ei, E, bhist, NBKT, NBLKE,
                                                 x, xb, n4, ncvt,
                                                 W0, W1, W2, Wt0, Wt1, Wt2,
                                                 bufH, t3, FOUT, N);
  k_scan_a<<<GS, 256, 0, stream>>>(bhist, lscan, partials, T);
  k_scan_b<<<1, 1024, 0, stream>>>(partials, GS);
  k_scan_c<<<GS, 256, 0, stream>>>(lscan, bhist, partials, scanned, bucketPtr,
                                   T, NBLKE, NBKT, E);
  b_scatter<<<NBLKE, 256, 0, stream>>>(ei, E, scanned, ebuf, NBKT, NBLKE);
  b_pass2<<<NBKT, 256, 0, stream>>>(ebuf, bucketPtr, rowptr, colsrc, N, NBKT, E);

  int gagg = (N + 3) / 4;
  int ggemm = (N + 63) / 64;
  // layer 1: h1 = relu(agg(x)@W0+b0)
  k_agg128b<<<gagg, 256, 0, stream>>>((const char*)xb, rowptr, colsrc,
                                      (unsigned int*)bufA, N);
  k_gemm<0><<<ggemm, 256, 0, stream>>>(bufA, Wt0, b0, nullptr, bufH, N);
  // layers 2+3a: t3 = relu(agg(h1)@W1+b1) @ W2   (h2 never materialized)
  k_agg128b<<<gagg, 256, 0, stream>>>((const char*)bufH, rowptr, colsrc,
                                      (unsigned int*)bufA, N);
  k_gemm<1><<<ggemm, 256, 0, stream>>>(bufA, Wt1, b1, Wt2, t3, N);
  // layer 3b: out = agg(t3) + b2
  k_agg40<<<gagg, 256, 0, stream>>>((const char*)t3, rowptr, colsrc, b2, out, N);
}

// Round 10
// 277.502 us; speedup vs baseline: 1.0617x; 1.0317x over previous
//
#include <hip/hip_runtime.h>

// ---------------------------------------------------------------------------
// GCN: out = agg(relu(agg(relu(agg(x)W0+b0))W1+b1) @ W2) + b2
// R10 = R9 + LDS-staged coalesced colsrc writes in pass2 (+fallback),
//       EPB 4096 (scatter TLP/fragmentation midpoint),
//       __launch_bounds__(256,8) on agg kernels.
// ---------------------------------------------------------------------------

typedef short bf16x8 __attribute__((ext_vector_type(8)));
typedef float f32x4  __attribute__((ext_vector_type(4)));

#define EPB 4096        // edges per routing block
#define P2CAP 6144      // pass2 LDS staging capacity (edges)

__device__ __forceinline__ float bflo(unsigned int v) {
  union { float f; unsigned int i; } w; w.i = v << 16; return w.f;
}
__device__ __forceinline__ float bfhi(unsigned int v) {
  union { float f; unsigned int i; } w; w.i = v & 0xffff0000u; return w.f;
}
__device__ __forceinline__ unsigned short f2bf(float f) {
  union { float f; unsigned int i; } w; w.f = f;
  unsigned int b = w.i;
  unsigned int r = (b + 0x7fffu + ((b >> 16) & 1u)) >> 16;   // RNE
  return (unsigned short)r;
}

__device__ __forceinline__ int edge_at(const void* ei, int is64, long long pos) {
  if (is64) return (int)((const long long*)ei)[pos];
  return ((const int*)ei)[pos];
}

__device__ __forceinline__ void agg_accum(float* a, uint4 v) {
  a[0] += bflo(v.x); a[1] += bfhi(v.x);
  a[2] += bflo(v.y); a[3] += bfhi(v.y);
  a[4] += bflo(v.z); a[5] += bfhi(v.z);
  a[6] += bflo(v.w); a[7] += bfhi(v.w);
}

// --------------------------- mega prep --------------------------------------
__global__ __launch_bounds__(256) void k_prep(const void* __restrict__ ei, int E,
                                              int* __restrict__ bhist,
                                              int NBKT, int NBLKE,
                                              const float* __restrict__ x,
                                              unsigned short* __restrict__ xb,
                                              long long n4, int ncvt,
                                              const float* __restrict__ W0,
                                              const float* __restrict__ W1,
                                              const float* __restrict__ W2,
                                              unsigned short* __restrict__ Wt0,
                                              unsigned short* __restrict__ Wt1,
                                              unsigned short* __restrict__ Wt2,
                                              unsigned short* __restrict__ bufH,
                                              unsigned short* __restrict__ t3,
                                              int FOUT, int N) {
  int blk = blockIdx.x, tid = threadIdx.x;
  if (blk < NBLKE) {
    __shared__ int h[512];
    __shared__ int s_is64;
    if (tid < 64) {
      int v = ((const int*)ei)[2 * tid + 1];
      unsigned long long m = __ballot(v != 0);
      if (tid == 0) s_is64 = (m == 0ull) ? 1 : 0;
    }
    for (int i = tid; i < NBKT; i += 256) h[i] = 0;
    __syncthreads();
    int is64 = s_is64;
    int base = blk * EPB;
    int cnt = min(EPB, E - base);
    for (int i = tid; i < cnt; i += 256) {
      int d = edge_at(ei, is64, (long long)E + base + i);
      atomicAdd(&h[d >> 8], 1);
    }
    __syncthreads();
    for (int i = tid; i < NBKT; i += 256) bhist[i * NBLKE + blk] = h[i];
  } else if (blk < NBLKE + ncvt) {
    long long i = (long long)(blk - NBLKE) * 256 + tid;
    if (i < n4) {
      float4 v = *reinterpret_cast<const float4*>(x + i * 4);
      ushort4 o;
      o.x = f2bf(v.x); o.y = f2bf(v.y); o.z = f2bf(v.z); o.w = f2bf(v.w);
      *reinterpret_cast<ushort4*>(xb + i * 4) = o;
    }
  } else {
    int idx = (blk - NBLKE - ncvt) * 256 + tid;
    if (idx < 16384) {
      int c = idx >> 7, k = idx & 127;
      Wt0[c * 128 + k] = f2bf(W0[k * 128 + c]);
    } else if (idx < 32768) {
      int t = idx - 16384;
      int c = t >> 7, k = t & 127;
      Wt1[c * 128 + k] = f2bf(W1[k * 128 + c]);
    } else if (idx < 40960) {                    // Wt2: 64 cols x 128
      int t = idx - 32768;
      int c = t >> 7, k = t & 127;
      Wt2[c * 128 + k] = (c < FOUT) ? f2bf(W2[k * FOUT + c]) : (unsigned short)0;
    } else if (idx < 41280) {                    // zero rows at index N
      int t = idx - 40960;
      if (t < 128)       xb[(size_t)N * 128 + t] = 0;
      else if (t < 256)  bufH[(size_t)N * 128 + (t - 128)] = 0;
      else               t3[(size_t)N * 64 + (t - 256)] = 0;
    }
  }
}

// --------------------------- scans ------------------------------------------
__global__ void k_scan_a(const int* __restrict__ vals, int* __restrict__ lscan,
                         int* __restrict__ partials, int n) {
  __shared__ int sm[256];
  int tid = threadIdx.x;
  int i = blockIdx.x * 256 + tid;
  int v = (i < n) ? vals[i] : 0;
  sm[tid] = v;
  __syncthreads();
  for (int off = 1; off < 256; off <<= 1) {
    int t = (tid >= off) ? sm[tid - off] : 0;
    __syncthreads();
    sm[tid] += t;
    __syncthreads();
  }
  if (i < n) lscan[i] = sm[tid];
  if (tid == 255) partials[blockIdx.x] = sm[255];
}

// exclusive scan of up to 2048 partials (2 elems/thread, 1024 threads)
__global__ void k_scan_b(int* __restrict__ partials, int nb) {
  __shared__ int sm[1024];
  int tid = threadIdx.x;
  int i0 = 2 * tid, i1 = 2 * tid + 1;
  int v0 = (i0 < nb) ? partials[i0] : 0;
  int v1 = (i1 < nb) ? partials[i1] : 0;
  int s = v0 + v1;
  sm[tid] = s;
  __syncthreads();
  for (int off = 1; off < 1024; off <<= 1) {
    int t = (tid >= off) ? sm[tid - off] : 0;
    __syncthreads();
    sm[tid] += t;
    __syncthreads();
  }
  int excl = sm[tid] - s;
  if (i0 < nb) partials[i0] = excl;
  if (i1 < nb) partials[i1] = excl + v0;
}

__global__ void k_scan_c(const int* __restrict__ lscan, const int* __restrict__ vals,
                         const int* __restrict__ partials, int* __restrict__ scanned,
                         int* __restrict__ bucketPtr, int n, int NBLKE, int NBKT, int E) {
  int i = blockIdx.x * 256 + threadIdx.x;
  if (i >= n) return;
  int v = lscan[i] - vals[i] + partials[blockIdx.x];
  scanned[i] = v;
  int q = i / NBLKE;
  if (i - q * NBLKE == 0) bucketPtr[q] = v;
  if (i == 0) bucketPtr[NBKT] = E;
}

// --------------------------- scatter + pass2 --------------------------------
__global__ __launch_bounds__(256) void b_scatter(const void* __restrict__ ei, int E,
                                                 const int* __restrict__ scanned,
                                                 unsigned* __restrict__ ebuf,
                                                 int NBKT, int NBLKE) {
  __shared__ int base[512];
  __shared__ int s_is64;
  int blk = blockIdx.x, tid = threadIdx.x;
  if (tid < 64) {
    int v = ((const int*)ei)[2 * tid + 1];
    unsigned long long m = __ballot(v != 0);
    if (tid == 0) s_is64 = (m == 0ull) ? 1 : 0;
  }
  for (int i = tid; i < NBKT; i += 256) base[i] = scanned[i * NBLKE + blk];
  __syncthreads();
  int is64 = s_is64;
  int b0 = blk * EPB;
  int cnt = min(EPB, E - b0);
  for (int i = tid; i < cnt; i += 256) {
    int d = edge_at(ei, is64, (long long)E + b0 + i);
    int s = edge_at(ei, is64, b0 + i);
    int pos = atomicAdd(&base[d >> 8], 1);
    ebuf[pos] = (unsigned)s | ((unsigned)(d & 255) << 24);
  }
}

// counting sort per bucket; colsrc written via LDS staging -> fully coalesced
// streaming of the contiguous bucket region (fallback to direct writes if the
// bucket exceeds P2CAP edges).
__global__ __launch_bounds__(256) void b_pass2(const unsigned* __restrict__ ebuf,
                                               const int* __restrict__ bucketPtr,
                                               int* __restrict__ rowptr,
                                               int* __restrict__ colsrc,
                                               int N, int NBKT, int E) {
  __shared__ int hist[256], excl[256], cur[256], sm[256];
  __shared__ int stage[P2CAP];
  int b = blockIdx.x, tid = threadIdx.x;
  hist[tid] = 0;
  __syncthreads();
  int beg = bucketPtr[b], end = bucketPtr[b + 1];
  int cnt = end - beg;
  for (int i = beg + tid; i < end; i += 256)
    atomicAdd(&hist[ebuf[i] >> 24], 1);
  __syncthreads();
  int v = hist[tid];
  sm[tid] = v;
  __syncthreads();
  for (int off = 1; off < 256; off <<= 1) {
    int t = (tid >= off) ? sm[tid - off] : 0;
    __syncthreads();
    sm[tid] += t;
    __syncthreads();
  }
  excl[tid] = sm[tid] - v;
  cur[tid] = 0;
  __syncthreads();
  int nb0 = b << 8;
  if (nb0 + tid < N) rowptr[nb0 + tid] = beg + excl[tid];
  if (b == 0 && tid == 0) rowptr[N] = E;
  bool st = (cnt <= P2CAP);
  for (int i = beg + tid; i < end; i += 256) {
    unsigned e2 = ebuf[i];
    int dl = (int)(e2 >> 24);
    int r = atomicAdd(&cur[dl], 1);
    int pos = excl[dl] + r;
    int val = (int)(e2 & 0xFFFFFFu);
    if (st) stage[pos] = val;
    else    colsrc[beg + pos] = val;
  }
  __syncthreads();
  if (st) {
    for (int i = tid; i < cnt; i += 256) colsrc[beg + i] = stage[i];
  }
}

// --------------------------- aggregation ------------------------------------
// 128-wide bf16 agg: 1 wave/node, uniform trip count, zero-row predication,
// 4x 16B gathers in flight per lane (R7 sweet spot: 28 VGPR).
__global__ __launch_bounds__(256, 8) void k_agg128b(
    const char* __restrict__ Hb,
    const int* __restrict__ rowptr, const int* __restrict__ colsrc,
    unsigned int* __restrict__ out, int N) {
  int node = blockIdx.x * 4 + (threadIdx.x >> 6);
  if (node >= N) return;
  int l = threadIdx.x & 63, sub = l >> 4, fl = l & 15;
  int beg = rowptr[node], end = rowptr[node + 1];
  int nb = (end - beg + 15) >> 4;
  const unsigned zoff = (unsigned)N << 8;
  unsigned flo = (unsigned)fl * 16u;
  float a[8] = {0.f, 0.f, 0.f, 0.f, 0.f, 0.f, 0.f, 0.f};
  for (int t = 0; t < nb; ++t) {
    int e = beg + t * 16 + sub * 4;
    int em = end - 1;
    int i0 = e, i1 = e + 1, i2 = e + 2, i3 = e + 3;
    int s0 = colsrc[i0 < end ? i0 : em];
    int s1 = colsrc[i1 < end ? i1 : em];
    int s2 = colsrc[i2 < end ? i2 : em];
    int s3 = colsrc[i3 < end ? i3 : em];
    unsigned o0 = (i0 < end ? ((unsigned)s0 << 8) : zoff) + flo;
    unsigned o1 = (i1 < end ? ((unsigned)s1 << 8) : zoff) + flo;
    unsigned o2 = (i2 < end ? ((unsigned)s2 << 8) : zoff) + flo;
    unsigned o3 = (i3 < end ? ((unsigned)s3 << 8) : zoff) + flo;
    uint4 v0 = *reinterpret_cast<const uint4*>(Hb + o0);
    uint4 v1 = *reinterpret_cast<const uint4*>(Hb + o1);
    uint4 v2 = *reinterpret_cast<const uint4*>(Hb + o2);
    uint4 v3 = *reinterpret_cast<const uint4*>(Hb + o3);
    agg_accum(a, v0); agg_accum(a, v1); agg_accum(a, v2); agg_accum(a, v3);
  }
  #pragma unroll
  for (int k = 0; k < 8; ++k) {
    a[k] += __shfl_xor(a[k], 16);
    a[k] += __shfl_xor(a[k], 32);
  }
  if (sub == 0) {
    uint4 o;
    o.x = ((unsigned)f2bf(a[1]) << 16) | f2bf(a[0]);
    o.y = ((unsigned)f2bf(a[3]) << 16) | f2bf(a[2]);
    o.z = ((unsigned)f2bf(a[5]) << 16) | f2bf(a[4]);
    o.w = ((unsigned)f2bf(a[7]) << 16) | f2bf(a[6]);
    *reinterpret_cast<uint4*>(out + (size_t)node * 64 + fl * 4) = o;
  }
}

// 40-wide final agg from padded [N+1][64] bf16; out f32 [N][40] + b2.
__global__ __launch_bounds__(256, 8) void k_agg40(
    const char* __restrict__ Tb,
    const int* __restrict__ rowptr, const int* __restrict__ colsrc,
    const float* __restrict__ b2, float* __restrict__ out, int N) {
  int node = blockIdx.x * 4 + (threadIdx.x >> 6);
  if (node >= N) return;
  int l = threadIdx.x & 63, sub = l >> 4, fl = l & 15;
  int beg = rowptr[node], end = rowptr[node + 1];
  int nb = (end - beg + 15) >> 4;
  const unsigned zoff = (unsigned)N << 7;
  unsigned flo = (unsigned)fl * 8u;
  float a[4] = {0.f, 0.f, 0.f, 0.f};
  if (fl < 10) {
    for (int t = 0; t < nb; ++t) {
      int e = beg + t * 16 + sub * 4;
      int em = end - 1;
      int i0 = e, i1 = e + 1, i2 = e + 2, i3 = e + 3;
      int s0 = colsrc[i0 < end ? i0 : em];
      int s1 = colsrc[i1 < end ? i1 : em];
      int s2 = colsrc[i2 < end ? i2 : em];
      int s3 = colsrc[i3 < end ? i3 : em];
      unsigned o0 = (i0 < end ? ((unsigned)s0 << 7) : zoff) + flo;
      unsigned o1 = (i1 < end ? ((unsigned)s1 << 7) : zoff) + flo;
      unsigned o2 = (i2 < end ? ((unsigned)s2 << 7) : zoff) + flo;
      unsigned o3 = (i3 < end ? ((unsigned)s3 << 7) : zoff) + flo;
      uint2 v0 = *reinterpret_cast<const uint2*>(Tb + o0);
      uint2 v1 = *reinterpret_cast<const uint2*>(Tb + o1);
      uint2 v2 = *reinterpret_cast<const uint2*>(Tb + o2);
      uint2 v3 = *reinterpret_cast<const uint2*>(Tb + o3);
      a[0] += (bflo(v0.x) + bflo(v1.x)) + (bflo(v2.x) + bflo(v3.x));
      a[1] += (bfhi(v0.x) + bfhi(v1.x)) + (bfhi(v2.x) + bfhi(v3.x));
      a[2] += (bflo(v0.y) + bflo(v1.y)) + (bflo(v2.y) + bflo(v3.y));
      a[3] += (bfhi(v0.y) + bfhi(v1.y)) + (bfhi(v2.y) + bfhi(v3.y));
    }
  }
  #pragma unroll
  for (int k = 0; k < 4; ++k) {
    a[k] += __shfl_xor(a[k], 16);
    a[k] += __shfl_xor(a[k], 32);
  }
  if (sub == 0 && fl < 10) {
    float4 o;
    o.x = a[0] + b2[fl * 4 + 0];
    o.y = a[1] + b2[fl * 4 + 1];
    o.z = a[2] + b2[fl * 4 + 2];
    o.w = a[3] + b2[fl * 4 + 3];
    *reinterpret_cast<float4*>(out + (size_t)node * 40 + fl * 4) = o;
  }
}

// --------------------------- GEMM (MFMA bf16) -------------------------------
// CHAIN=0: C[N][128] = relu(A@Wt + bias)
// CHAIN=1: C[N][64]  = (relu(A@Wt + bias)) @ Wt2   (C2 staged in wave-LDS)
template <int CHAIN>
__global__ __launch_bounds__(256) void k_gemm(const unsigned short* __restrict__ A,
                                              const unsigned short* __restrict__ Wt,
                                              const float* __restrict__ bias,
                                              const unsigned short* __restrict__ Wt2,
                                              unsigned short* __restrict__ C, int N) {
  __shared__ unsigned short sh16[CHAIN ? 4 * 2048 : 64];   // 16 KB when chaining
  int tid = threadIdx.x;
  int w = tid >> 6, l = tid & 63;
  int sub = l >> 4, fl = l & 15;
  int r0 = blockIdx.x * 64 + w * 16;
  int arow = r0 + fl;
  if (arow >= N) arow = N - 1;
  int kk = sub * 8;
  bf16x8 af[4];
  #pragma unroll
  for (int ks = 0; ks < 4; ++ks)
    af[ks] = *reinterpret_cast<const bf16x8*>(A + (size_t)arow * 128 + ks * 32 + kk);

  int ccol = fl;
  int crow0 = r0 + sub * 4;

  if (CHAIN == 0) {
    #pragma unroll
    for (int cf = 0; cf < 8; ++cf) {
      f32x4 acc = {0.f, 0.f, 0.f, 0.f};
      const unsigned short* wp = Wt + (size_t)(cf * 16 + ccol) * 128 + kk;
      #pragma unroll
      for (int ks = 0; ks < 4; ++ks) {
        bf16x8 b = *reinterpret_cast<const bf16x8*>(wp + ks * 32);
        acc = __builtin_amdgcn_mfma_f32_16x16x32_bf16(af[ks], b, acc, 0, 0, 0);
      }
      float bv = bias[cf * 16 + ccol];
      #pragma unroll
      for (int r = 0; r < 4; ++r) {
        int gr = crow0 + r;
        if (gr < N)
          C[(size_t)gr * 128 + cf * 16 + ccol] = f2bf(fmaxf(acc[r] + bv, 0.f));
      }
    }
  } else {
    unsigned short* my = &sh16[w * 2048];
    #pragma unroll
    for (int cf = 0; cf < 8; ++cf) {
      f32x4 acc = {0.f, 0.f, 0.f, 0.f};
      const unsigned short* wp = Wt + (size_t)(cf * 16 + ccol) * 128 + kk;
      #pragma unroll
      for (int ks = 0; ks < 4; ++ks) {
        bf16x8 b = *reinterpret_cast<const bf16x8*>(wp + ks * 32);
        acc = __builtin_amdgcn_mfma_f32_16x16x32_bf16(af[ks], b, acc, 0, 0, 0);
      }
      float bv = bias[cf * 16 + ccol];
      int col = cf * 16 + ccol;
      int chunk = col >> 3;
      #pragma unroll
      for (int r = 0; r < 4; ++r) {
        int row = sub * 4 + r;
        my[row * 128 + ((chunk ^ row) << 3) + (col & 7)] = f2bf(fmaxf(acc[r] + bv, 0.f));
      }
    }
    // second GEMM: A3 = C2 tile (rows = fl), k-chunks swizzle-read from LDS
    bf16x8 af3[4];
    #pragma unroll
    for (int ks = 0; ks < 4; ++ks) {
      int c = ks * 4 + sub;
      af3[ks] = *reinterpret_cast<const bf16x8*>(&my[fl * 128 + ((c ^ fl) << 3)]);
    }
    #pragma unroll
    for (int cf = 0; cf < 4; ++cf) {                   // 64 cols
      f32x4 acc = {0.f, 0.f, 0.f, 0.f};
      const unsigned short* wp = Wt2 + (size_t)(cf * 16 + ccol) * 128 + kk;
      #pragma unroll
      for (int ks = 0; ks < 4; ++ks) {
        bf16x8 b = *reinterpret_cast<const bf16x8*>(wp + ks * 32);
        acc = __builtin_amdgcn_mfma_f32_16x16x32_bf16(af3[ks], b, acc, 0, 0, 0);
      }
      #pragma unroll
      for (int r = 0; r < 4; ++r) {
        int gr = crow0 + r;
        if (gr < N)
          C[(size_t)gr * 64 + cf * 16 + ccol] = f2bf(acc[r]);
      }
    }
  }
}

extern "C" void kernel_launch(void* const* d_in, const int* in_sizes, int n_in,
                              void* d_out, int out_size, void* d_ws, size_t ws_size,
                              hipStream_t stream) {
  const float* x  = (const float*)d_in[0];
  const void*  ei = d_in[1];
  const float* W0 = (const float*)d_in[2];
  const float* b0 = (const float*)d_in[3];
  const float* W1 = (const float*)d_in[4];
  const float* b1 = (const float*)d_in[5];
  const float* W2 = (const float*)d_in[6];
  const float* b2 = (const float*)d_in[7];
  float* out = (float*)d_out;

  const int N = in_sizes[0] / 128;     // 100000
  const int E = in_sizes[1] / 2;       // 1600000
  const int FOUT = in_sizes[6] / 128;  // 40

  const int NBLKE = (E + EPB - 1) / EPB;        // 391
  const int NBKT  = (N + 255) / 256;            // 391
  const int T     = NBKT * NBLKE;               // 152,881
  const int GS    = (T + 255) / 256;            // 598 (<=2048 for scan_b)

  char* wp = (char*)d_ws;
  auto alloc = [&](size_t bytes) -> void* {
    void* p = (void*)wp;
    wp += (bytes + 255) & ~(size_t)255;
    return p;
  };
  unsigned short* xb   = (unsigned short*)alloc((size_t)(N + 1) * 128 * 2);
  unsigned short* bufA = (unsigned short*)alloc((size_t)N * 128 * 2);
  unsigned short* bufH = (unsigned short*)alloc((size_t)(N + 1) * 128 * 2);
  unsigned short* t3   = (unsigned short*)alloc((size_t)(N + 1) * 64 * 2);
  unsigned short* Wt0  = (unsigned short*)alloc(128 * 128 * 2);
  unsigned short* Wt1  = (unsigned short*)alloc(128 * 128 * 2);
  unsigned short* Wt2  = (unsigned short*)alloc(64 * 128 * 2);
  unsigned* ebuf = (unsigned*)alloc((size_t)E * 4);
  int* colsrc   = (int*)alloc((size_t)E * 4);
  int* rowptr   = (int*)alloc((size_t)(N + 1) * 4);
  int* bhist    = (int*)alloc((size_t)T * 4);
  int* lscan    = (int*)alloc((size_t)T * 4);
  int* scanned  = (int*)alloc((size_t)T * 4);
  int* partials = (int*)alloc(8192);
  int* bucketPtr= (int*)alloc((size_t)(NBKT + 1) * 4);

  long long n4 = (long long)N * 32;
  int ncvt = (int)((n4 + 255) / 256);           // 12500
  int nwt  = (40960 + 320 + 255) / 256;         // 162

  k_prep<<<NBLKE + ncvt + nwt, 256, 0, stream>>>(ei, E, bhist, NBKT, NBLKE,
                                                 x, xb, n4, ncvt,
                                                 W0, W1, W2, Wt0, Wt1, Wt2,
                                                 bufH, t3, FOUT, N);
  k_scan_a<<<GS, 256, 0, stream>>>(bhist, lscan, partials, T);
  k_scan_b<<<1, 1024, 0, stream>>>(partials, GS);
  k_scan_c<<<GS, 256, 0, stream>>>(lscan, bhist, partials, scanned, bucketPtr,
                                   T, NBLKE, NBKT, E);
  b_scatter<<<NBLKE, 256, 0, stream>>>(ei, E, scanned, ebuf, NBKT, NBLKE);
  b_pass2<<<NBKT, 256, 0, stream>>>(ebuf, bucketPtr, rowptr, colsrc, N, NBKT, E);

  int gagg = (N + 3) / 4;
  int ggemm = (N + 63) / 64;
  // layer 1: h1 = relu(agg(x)@W0+b0)
  k_agg128b<<<gagg, 256, 0, stream>>>((const char*)xb, rowptr, colsrc,
                                      (unsigned int*)bufA, N);
  k_gemm<0><<<ggemm, 256, 0, stream>>>(bufA, Wt0, b0, nullptr, bufH, N);
  // layers 2+3a: t3 = relu(agg(h1)@W1+b1) @ W2   (h2 never materialized)
  k_agg128b<<<gagg, 256, 0, stream>>>((const char*)bufH, rowptr, colsrc,
                                      (unsigned int*)bufA, N);
  k_gemm<1><<<ggemm, 256, 0, stream>>>(bufA, Wt1, b1, Wt2, t3, N);
  // layer 3b: out = agg(t3) + b2
  k_agg40<<<gagg, 256, 0, stream>>>((const char*)t3, rowptr, colsrc, b2, out, N);
}